// Round 4
// baseline (494.607 us; speedup 1.0000x reference)
//
#include <hip/hip_runtime.h>
#include <math.h>

#define B_ 4
#define L_ 4096
#define D_ 1024
#define A_ 64
#define FF_ 2048
#define N_ (B_*L_)
#define EPS_ 1e-6f
#define CHUNK_ 128
#define NCHUNK_ (L_/CHUNK_)

typedef __attribute__((ext_vector_type(8))) short bf16x8;
typedef __attribute__((ext_vector_type(4))) short s16x4;
typedef __attribute__((ext_vector_type(4))) float f32x4;

static __device__ __forceinline__ float sigmoidf_(float x) { return 1.f/(1.f+expf(-x)); }
static __device__ __forceinline__ float siluf_(float x)    { return x/(1.f+expf(-x)); }

static __device__ __forceinline__ unsigned short f2bf(float f) {
    unsigned u = __float_as_uint(f);
    u += 0x7fffu + ((u >> 16) & 1u);        // RNE
    return (unsigned short)(u >> 16);
}

// async global->LDS, 16B per lane; lds ptr wave-uniform (HW adds lane*16)
static __device__ __forceinline__ void gload16(const short* g, short* l) {
    __builtin_amdgcn_global_load_lds(
        (const __attribute__((address_space(1))) void*)g,
        (__attribute__((address_space(3))) void*)l, 16, 0, 0);
}

// ---------------- rms (one wave per row) ----------------
__global__ __launch_bounds__(256) void rms_kernel(const float* __restrict__ x,
                                                  float* __restrict__ rms)
{
    int row  = blockIdx.x*4 + (threadIdx.x>>6);
    int lane = threadIdx.x & 63;
    const float4* xr = (const float4*)(x + (size_t)row*D_);
    float s = 0.f;
#pragma unroll
    for (int j = 0; j < 4; j++) {
        float4 v = xr[lane + 64*j];
        s += v.x*v.x + v.y*v.y + v.z*v.z + v.w*v.w;
    }
#pragma unroll
    for (int off = 32; off > 0; off >>= 1) s += __shfl_xor(s, off);
    if (lane == 0) rms[row] = rsqrtf(s*(1.f/(float)D_) + EPS_);
}

// ---------------- SSM scan phase 1 ----------------
__global__ __launch_bounds__(64) void scan1_kernel(
    const float* __restrict__ x, const float* __restrict__ rms1,
    const float* __restrict__ n1w, const float* __restrict__ bw,
    const float* __restrict__ araw, float* __restrict__ cpart)
{
    int d = blockIdx.x*64 + threadIdx.x;
    int c = blockIdx.y;
    int b = blockIdx.z;
    float a = sigmoidf_(araw[d]);
    float w = n1w[d]*bw[d];
    float h = 0.f;
    size_t base = ((size_t)b*L_ + (size_t)c*CHUNK_)*D_ + d;
    const float* rp = rms1 + b*L_ + c*CHUNK_;
#pragma unroll 8
    for (int t = 0; t < CHUNK_; t++) {
        float u = x[base + (size_t)t*D_] * rp[t] * w;
        h = a*h + u;
    }
    cpart[((size_t)b*NCHUNK_ + c)*D_ + d] = h;
}

// ---------------- SSM scan phase 2 ----------------
__global__ __launch_bounds__(256) void scan2_kernel(
    const float* __restrict__ araw, const float* __restrict__ cpart,
    float* __restrict__ cin)
{
    int idx = blockIdx.x*256 + threadIdx.x;
    int b = idx >> 10;
    int d = idx & (D_-1);
    float a = sigmoidf_(araw[d]);
    float aT = a;
#pragma unroll
    for (int i = 0; i < 7; i++) aT *= aT;     // a^128
    float cy = 0.f;
    for (int c = 0; c < NCHUNK_; c++) {
        size_t o = ((size_t)b*NCHUNK_ + c)*D_ + d;
        cin[o] = cy;
        cy = aT*cy + cpart[o];
    }
}

// ---------------- SSM scan phase 3: writes x_ssm f32 + bf16 ----------------
__global__ __launch_bounds__(64) void scan3_kernel(
    const float* __restrict__ x, const float* __restrict__ rms1,
    const float* __restrict__ n1w, const float* __restrict__ bw,
    const float* __restrict__ cw, const float* __restrict__ araw,
    const float* __restrict__ cin, float* __restrict__ x_ssm,
    short* __restrict__ xsb)
{
    int d = blockIdx.x*64 + threadIdx.x;
    int c = blockIdx.y;
    int b = blockIdx.z;
    float a = sigmoidf_(araw[d]);
    float w = n1w[d]*bw[d];
    float cwd = cw[d];
    float h = cin[((size_t)b*NCHUNK_ + c)*D_ + d];
    size_t base = ((size_t)b*L_ + (size_t)c*CHUNK_)*D_ + d;
    const float* rp = rms1 + b*L_ + c*CHUNK_;
#pragma unroll 8
    for (int t = 0; t < CHUNK_; t++) {
        size_t p = base + (size_t)t*D_;
        float xv = x[p];
        h = a*h + xv * rp[t] * w;
        float o = xv + h*cwd;
        x_ssm[p] = o;
        xsb[p] = (short)f2bf(o);
    }
}

// ---------------- gate ----------------
__global__ __launch_bounds__(256) void gate_kernel(
    const float* __restrict__ xs, const float* __restrict__ Wg,
    const float* __restrict__ gb, float* __restrict__ gate)
{
    int row  = blockIdx.x*4 + (threadIdx.x>>6);
    int lane = threadIdx.x & 63;
    const float4* xr = (const float4*)(xs + (size_t)row*D_);
    const float4* wr = (const float4*)Wg;
    float s = 0.f;
#pragma unroll
    for (int j = 0; j < 4; j++) {
        float4 xv = xr[lane + 64*j];
        float4 wv = wr[lane + 64*j];
        s += xv.x*wv.x + xv.y*wv.y + xv.z*wv.z + xv.w*wv.w;
    }
#pragma unroll
    for (int off = 32; off > 0; off >>= 1) s += __shfl_xor(s, off);
    if (lane == 0) gate[row] = sigmoidf_(s + gb[0]);
}

// ---------------- sliding-window attention (f32 in, bf16 out) ----------------
__global__ __launch_bounds__(256) void attn_kernel(
    const float* __restrict__ qm, const float* __restrict__ km,
    const float* __restrict__ vm, short* __restrict__ om)
{
    __shared__ float KV[128][68];
    int b  = blockIdx.y;
    int l0 = blockIdx.x*64;
    int t  = threadIdx.x;
    int r  = t >> 2;
    int qq = t & 3;

#pragma unroll
    for (int i = 0; i < 8; i++) {
        int lin = i*256 + t;
        int row = lin >> 4;
        int f4  = lin & 15;
        int gl  = l0 - 64 + row;
        float4 val = make_float4(0.f,0.f,0.f,0.f);
        if (gl >= 0) val = *(const float4*)(km + ((size_t)b*L_ + gl)*A_ + f4*4);
        *(float4*)&KV[row][f4*4] = val;
    }
    float4 qreg[16];
    {
        const float* qrow = qm + ((size_t)b*L_ + l0 + r)*A_;
#pragma unroll
        for (int j = 0; j < 16; j++) qreg[j] = *(const float4*)(qrow + j*4);
    }
    __syncthreads();

    float s[16];
#pragma unroll
    for (int wi = 0; wi < 16; wi++) {
        int w  = qq*16 + wi;
        int tr = r + w + 1;
        float dot = 0.f;
#pragma unroll
        for (int j = 0; j < 16; j++) {
            float4 kv = *(const float4*)&KV[tr][j*4];
            dot += qreg[j].x*kv.x + qreg[j].y*kv.y + qreg[j].z*kv.z + qreg[j].w*kv.w;
        }
        s[wi] = (l0 + r - 63 + w >= 0) ? dot*0.125f : -INFINITY;
    }
    float mx = s[0];
#pragma unroll
    for (int wi = 1; wi < 16; wi++) mx = fmaxf(mx, s[wi]);
    mx = fmaxf(mx, __shfl_xor(mx, 1));
    mx = fmaxf(mx, __shfl_xor(mx, 2));
    float sum = 0.f;
#pragma unroll
    for (int wi = 0; wi < 16; wi++) { s[wi] = expf(s[wi] - mx); sum += s[wi]; }
    sum += __shfl_xor(sum, 1);
    sum += __shfl_xor(sum, 2);
    float inv = 1.f/sum;
#pragma unroll
    for (int wi = 0; wi < 16; wi++) s[wi] *= inv;

    __syncthreads();
#pragma unroll
    for (int i = 0; i < 8; i++) {
        int lin = i*256 + t;
        int row = lin >> 4;
        int f4  = lin & 15;
        int gl  = l0 - 64 + row;
        float4 val = make_float4(0.f,0.f,0.f,0.f);
        if (gl >= 0) val = *(const float4*)(vm + ((size_t)b*L_ + gl)*A_ + f4*4);
        *(float4*)&KV[row][f4*4] = val;
    }
    __syncthreads();

    float4 acc[4];
#pragma unroll
    for (int ss = 0; ss < 4; ss++) acc[ss] = make_float4(0.f,0.f,0.f,0.f);
#pragma unroll
    for (int w = 0; w < 64; w++) {
        float pv = __shfl(s[w & 15], (t & 60) + (w >> 4));
        int tr = r + w + 1;
#pragma unroll
        for (int ss = 0; ss < 4; ss++) {
            float4 vv = *(const float4*)&KV[tr][qq*16 + ss*4];
            acc[ss].x += pv*vv.x; acc[ss].y += pv*vv.y;
            acc[ss].z += pv*vv.z; acc[ss].w += pv*vv.w;
        }
    }
    short* orow = om + ((size_t)b*L_ + l0 + r)*A_ + qq*16;
#pragma unroll
    for (int ss = 0; ss < 4; ss++) {
        s16x4 ov = { (short)f2bf(acc[ss].x), (short)f2bf(acc[ss].y),
                     (short)f2bf(acc[ss].z), (short)f2bf(acc[ss].w) };
        *(s16x4*)(orow + ss*4) = ov;
    }
}

// ---------------- transpose + f32->bf16 cast: in [R][C] f32 -> out [C][R] bf16 ----------------
__global__ __launch_bounds__(256) void cvt_transpose(
    const float* __restrict__ in, int R, int C, short* __restrict__ out)
{
    __shared__ short sh[64][68];
    int t  = threadIdx.x;
    int c0 = blockIdx.x * 64, r0 = blockIdx.y * 64;
    int rr = t >> 4, cc = (t & 15) * 4;
#pragma unroll
    for (int p = 0; p < 4; p++) {
        int r = p*16 + rr;
        float4 v = *(const float4*)(in + (size_t)(r0 + r)*C + c0 + cc);
        s16x4 sv = { (short)f2bf(v.x), (short)f2bf(v.y), (short)f2bf(v.z), (short)f2bf(v.w) };
        *(s16x4*)&sh[r][cc] = sv;
    }
    __syncthreads();
#pragma unroll
    for (int p = 0; p < 4; p++) {
        int c = p*16 + rr;
        s16x4 ov = { sh[cc+0][c], sh[cc+1][c], sh[cc+2][c], sh[cc+3][c] };
        *(s16x4*)(out + (size_t)(c0 + c)*R + r0 + cc) = ov;
    }
}

// ---------------- merged QKV weight transpose: 3x [D_][A_] f32 -> [A_][D_] bf16 ----------------
__global__ __launch_bounds__(256) void qkv_t3(
    const float* __restrict__ Wq, const float* __restrict__ Wk,
    const float* __restrict__ Wv, short* __restrict__ outall)
{
    __shared__ short sh[64][68];
    const float* in = (blockIdx.z == 0) ? Wq : (blockIdx.z == 1) ? Wk : Wv;
    short* out = outall + (size_t)blockIdx.z * A_ * D_;
    int t  = threadIdx.x;
    int r0 = blockIdx.y * 64;
    int rr = t >> 4, cc = (t & 15) * 4;
#pragma unroll
    for (int p = 0; p < 4; p++) {
        int r = p*16 + rr;
        float4 v = *(const float4*)(in + (size_t)(r0 + r)*A_ + cc);
        s16x4 sv = { (short)f2bf(v.x), (short)f2bf(v.y), (short)f2bf(v.z), (short)f2bf(v.w) };
        *(s16x4*)&sh[r][cc] = sv;
    }
    __syncthreads();
#pragma unroll
    for (int p = 0; p < 4; p++) {
        int c = p*16 + rr;
        s16x4 ov = { sh[cc+0][c], sh[cc+1][c], sh[cc+2][c], sh[cc+3][c] };
        *(s16x4*)(out + (size_t)c*D_ + r0 + cc) = ov;
    }
}

// ---------------- fused rmsnorm2 + bf16 cast ----------------
__global__ __launch_bounds__(256) void ff1prep(
    const float* __restrict__ xatt, const float* __restrict__ n2w,
    short* __restrict__ a1)
{
    int row  = blockIdx.x*4 + (threadIdx.x>>6);
    int lane = threadIdx.x & 63;
    const float4* xr = (const float4*)(xatt + (size_t)row*D_);
    const float4* wr = (const float4*)n2w;
    float4 v[4];
    float s = 0.f;
#pragma unroll
    for (int j = 0; j < 4; j++) {
        v[j] = xr[lane + 64*j];
        s += v[j].x*v[j].x + v[j].y*v[j].y + v[j].z*v[j].z + v[j].w*v[j].w;
    }
#pragma unroll
    for (int off = 32; off > 0; off >>= 1) s += __shfl_xor(s, off);
    float r = rsqrtf(s*(1.f/(float)D_) + EPS_);
#pragma unroll
    for (int j = 0; j < 4; j++) {
        float4 w = wr[lane + 64*j];
        s16x4 o = { (short)f2bf(v[j].x*r*w.x), (short)f2bf(v[j].y*r*w.y),
                    (short)f2bf(v[j].z*r*w.z), (short)f2bf(v[j].w*r*w.w) };
        *(s16x4*)(a1 + (size_t)row*D_ + (lane + 64*j)*4) = o;
    }
}

// ---------------- QKV: [N_][1024]bf16 @ [192][1024]bf16^T -> q,k,v f32 ----------------
__global__ __launch_bounds__(256) void qkv_mfma(
    const short* __restrict__ A, const short* __restrict__ BT,
    float* __restrict__ qo, float* __restrict__ ko, float* __restrict__ vo)
{
    __shared__ short As2[2][64*32];
    __shared__ short Bs2[2][192*32];
    const int t = threadIdx.x, l = t & 63, w = t >> 6;
    const size_t m0 = (size_t)blockIdx.x*64;
    const short* Ab = A + m0*D_;

    const int ar = w*16 + (l&15);
    const int offA = ar*32 + (((l>>4) ^ ((ar>>1)&3)) & 3)*8;
    int offB[12];
#pragma unroll
    for (int j = 0; j < 12; j++) {
        int br = j*16 + (l&15);
        offB[j] = br*32 + (((l>>4) ^ ((br>>1)&3)) & 3)*8;
    }

#define QSTG(bi, k0) { \
        { int r = t>>2; int lc = (t&3) ^ ((r>>1)&3); \
          gload16(Ab + (size_t)r*D_ + (k0) + lc*8, &As2[bi][(w*64)*8]); } \
        _Pragma("unroll") \
        for (int i_ = 0; i_ < 3; i_++) { \
            int s_ = i_*256 + t; int r = s_>>2; int lc = (s_&3) ^ ((r>>1)&3); \
            gload16(BT + (size_t)r*D_ + (k0) + lc*8, &Bs2[bi][(i_*256 + w*64)*8]); } }

    f32x4 acc[12];
    f32x4 zero = {0.f,0.f,0.f,0.f};
#pragma unroll
    for (int j = 0; j < 12; j++) acc[j] = zero;

    QSTG(0, 0);
    __syncthreads();
    int cur = 0;
    for (int kt = 0; kt < 32; kt++) {
        if (kt + 1 < 32) QSTG(cur^1, (kt+1)*32);
        bf16x8 af = *(const bf16x8*)&As2[cur][offA];
#pragma unroll
        for (int j = 0; j < 12; j++) {
            bf16x8 bfv = *(const bf16x8*)&Bs2[cur][offB[j]];
            acc[j] = __builtin_amdgcn_mfma_f32_16x16x32_bf16(af, bfv, acc[j], 0, 0, 0);
        }
        __syncthreads();
        cur ^= 1;
    }
#pragma unroll
    for (int j = 0; j < 12; j++) {
        int col = j*16 + (l&15);
        int mat = col >> 6, c = col & 63;
        float* dst = (mat == 0) ? qo : (mat == 1) ? ko : vo;
#pragma unroll
        for (int v = 0; v < 4; v++) {
            size_t row = m0 + w*16 + (l>>4)*4 + v;
            dst[row*A_ + c] = acc[j][v];
        }
    }
#undef QSTG
}

// ---------------- WO: out = resid + gate*(attn_bf16 @ wot^T), K=64 ----------------
__global__ __launch_bounds__(256) void gemm_wo(
    const short* __restrict__ A,   // attnb [N_][64]
    const short* __restrict__ BT,  // wot [1024][64]
    const float* __restrict__ gate, const float* __restrict__ resid,
    float* __restrict__ Cout)
{
    __shared__ short As3[128*64];
    __shared__ short Bs3[128*64];
    const int t = threadIdx.x, l = t & 63, w = t >> 6;
    const int wm = w >> 1, wn = w & 1;
    const size_t m0 = (size_t)blockIdx.x*128, n0 = (size_t)blockIdx.y*128;

#pragma unroll
    for (int i = 0; i < 4; i++) {
        int s = i*256 + t;
        int r = s >> 3, lc = (s&7) ^ (r&7);
        gload16(A  + (m0 + r)*64 + lc*8, &As3[(i*256 + w*64)*8]);
        gload16(BT + (n0 + r)*64 + lc*8, &Bs3[(i*256 + w*64)*8]);
    }
    __syncthreads();

    f32x4 acc[4][4];
    f32x4 zero = {0.f,0.f,0.f,0.f};
#pragma unroll
    for (int i = 0; i < 4; i++)
#pragma unroll
        for (int j = 0; j < 4; j++) acc[i][j] = zero;

#pragma unroll
    for (int kk = 0; kk < 2; kk++) {
        bf16x8 af[4], bfv[4];
#pragma unroll
        for (int i = 0; i < 4; i++) {
            int ar = wm*64 + i*16 + (l&15);
            int pch = (kk*4 + (l>>4)) ^ (ar&7);
            af[i] = *(const bf16x8*)&As3[ar*64 + pch*8];
        }
#pragma unroll
        for (int j = 0; j < 4; j++) {
            int br = wn*64 + j*16 + (l&15);
            int pch = (kk*4 + (l>>4)) ^ (br&7);
            bfv[j] = *(const bf16x8*)&Bs3[br*64 + pch*8];
        }
#pragma unroll
        for (int i = 0; i < 4; i++)
#pragma unroll
            for (int j = 0; j < 4; j++)
                acc[i][j] = __builtin_amdgcn_mfma_f32_16x16x32_bf16(af[i], bfv[j], acc[i][j], 0, 0, 0);
    }

#pragma unroll
    for (int i = 0; i < 4; i++) {
#pragma unroll
        for (int v = 0; v < 4; v++) {
            size_t row = m0 + wm*64 + i*16 + (l>>4)*4 + v;
            float g = gate[row];
#pragma unroll
            for (int j = 0; j < 4; j++) {
                size_t col = n0 + wn*64 + j*16 + (l&15);
                Cout[row*D_ + col] = resid[row*D_ + col] + g*acc[i][j][v];
            }
        }
    }
}

// ---------------- 8-phase 256x256 bf16 MFMA GEMM, BK=64, 8 waves, counted vmcnt ----------------
// LDS: A/B each 2 dbuf x 2 halves x [128][64] bf16 (16KB per half slot). 128 KiB total.
// Per K-tile: 4 phases = (A-half x B-half); each phase: ds_reads + 1 half-tile stage +
// counted vmcnt + barrier + lgkmcnt(0) + 16 MFMA + barrier.
// Stage schedule (tile kt): ph1: A1(kt+1), ph2: B1(kt+1), ph3: A0(kt+2), ph4: B0(kt+2).
// MODE 0: Cout bf16 = silu(acc); MODE 1: Cout f32 += acc (in-place residual)
template<int K, int MODE>
__global__ __launch_bounds__(512, 2) void gemm8p(
    const short* __restrict__ A,   // [M][K]
    const short* __restrict__ BT,  // [N][K]
    void* __restrict__ Cout, int ldc)
{
    __shared__ short LDSb[65536];    // shorts; A: [0,32768), B: [32768,65536)

    const int gx = gridDim.x, gy = gridDim.y;
    const int nwg = gx*gy;
    const int o = blockIdx.y*gx + blockIdx.x;
    const int q = nwg >> 3;
    const int swz = (o & 7)*q + (o >> 3);
    const int bx = swz / gy, by = swz % gy;

    const int t = threadIdx.x, l = t & 63, w = t >> 6;
    const int wm = w & 1;          // 2 M-groups
    const int wn = w >> 1;         // 4 N-groups
    const size_t m0 = (size_t)bx*256, n0 = (size_t)by*256;
    const short* Ab = A  + m0*(size_t)K;
    const short* Bb = BT + n0*(size_t)K;

    const int l15 = l & 15;
    const int l16 = (l >> 4)*16;       // k-group byte offset
    const int xsw = (l & 7)*16;        // XOR swizzle byte
    const int sc_row = l >> 3;         // staging: row within 8-row chunk
    const int sc_gc  = ((l&7) ^ sc_row)*8;  // staging: pre-swizzled global col elems

#define ASLOT(db,h) (((db)*2 + (h))*8192)
#define BSLOT(db,h) (32768 + ((db)*2 + (h))*8192)

    auto stage = [&](const short* src, int baseSlot, int h, int ktile) {
#pragma unroll
        for (int ii = 0; ii < 2; ii++) {
            int chunk = ii*8 + w;      // 16 chunks of 8 rows (1KB each)
            gload16(src + (size_t)(h*128 + chunk*8 + sc_row)*K + ktile*64 + sc_gc,
                    (short*)&LDSb[baseSlot + chunk*512]);
        }
    };
    auto rdA = [&](int db, int h, int ip, int kk) {
        int rl = ip*32 + wm*16 + l15;
        int cb = (kk*64 + l16) ^ xsw;
        return *(const bf16x8*)&LDSb[ASLOT(db,h) + rl*64 + (cb>>1)];
    };
    auto rdB = [&](int db, int jj, int kk) {
        int h = jj >> 1;
        int rl = (jj&1)*64 + wn*16 + l15;
        int cb = (kk*64 + l16) ^ xsw;
        return *(const bf16x8*)&LDSb[BSLOT(db,h) + rl*64 + (cb>>1)];
    };

    f32x4 acc[8][4];
    f32x4 zero = {0.f,0.f,0.f,0.f};
#pragma unroll
    for (int i = 0; i < 8; i++)
#pragma unroll
        for (int j = 0; j < 4; j++) acc[i][j] = zero;

    const int nk = K >> 6;
    bf16x8 ar[4][2], br[4][2];

    // prologue: tile0 all 4 halves + tile1 (A0,B0); wait A0(0),B0(0) landed
    stage(Ab, ASLOT(0,0), 0, 0);
    stage(Bb, BSLOT(0,0), 0, 0);
    stage(Ab, ASLOT(0,1), 1, 0);
    stage(Bb, BSLOT(0,1), 1, 0);
    stage(Ab, ASLOT(1,0), 0, 1);
    stage(Bb, BSLOT(1,0), 0, 1);
    asm volatile("s_waitcnt vmcnt(8)" ::: "memory");
    __builtin_amdgcn_s_barrier();

#pragma unroll 1
    for (int kt = 0; kt < nk; kt++) {
        const int db = kt & 1, dn = (kt+1) & 1;
        const bool s1 = (kt+1 < nk), s2 = (kt+2 < nk);

        // ---- phase 1: (A0,B0) ----
#pragma unroll
        for (int i2 = 0; i2 < 4; i2++)
#pragma unroll
            for (int kk = 0; kk < 2; kk++) ar[i2][kk] = rdA(db, 0, i2, kk);
#pragma unroll
        for (int jj = 0; jj < 2; jj++)
#pragma unroll
            for (int kk = 0; kk < 2; kk++) br[jj][kk] = rdB(db, jj, kk);
        if (s1) stage(Ab, ASLOT(dn,1), 1, kt+1);
        if (s1) { asm volatile("s_waitcnt vmcnt(6)" ::: "memory"); }
        else    { asm volatile("s_waitcnt vmcnt(0)" ::: "memory"); }
        __builtin_amdgcn_s_barrier();
        asm volatile("s_waitcnt lgkmcnt(0)" ::: "memory");
        __builtin_amdgcn_sched_barrier(0);
        __builtin_amdgcn_s_setprio(1);
#pragma unroll
        for (int i2 = 0; i2 < 4; i2++)
#pragma unroll
            for (int jj = 0; jj < 2; jj++)
#pragma unroll
                for (int kk = 0; kk < 2; kk++)
                    acc[i2][jj] = __builtin_amdgcn_mfma_f32_16x16x32_bf16(
                        ar[i2][kk], br[jj][kk], acc[i2][jj], 0, 0, 0);
        __builtin_amdgcn_s_setprio(0);
        __builtin_amdgcn_s_barrier();

        // ---- phase 2: (A0,B1) ----
#pragma unroll
        for (int jj = 0; jj < 2; jj++)
#pragma unroll
            for (int kk = 0; kk < 2; kk++) br[2+jj][kk] = rdB(db, 2+jj, kk);
        if (s1) stage(Bb, BSLOT(dn,1), 1, kt+1);
        if (s1) { asm volatile("s_waitcnt vmcnt(8)" ::: "memory"); }
        else    { asm volatile("s_waitcnt vmcnt(0)" ::: "memory"); }
        __builtin_amdgcn_s_barrier();
        asm volatile("s_waitcnt lgkmcnt(0)" ::: "memory");
        __builtin_amdgcn_sched_barrier(0);
        __builtin_amdgcn_s_setprio(1);
#pragma unroll
        for (int i2 = 0; i2 < 4; i2++)
#pragma unroll
            for (int jj = 0; jj < 2; jj++)
#pragma unroll
                for (int kk = 0; kk < 2; kk++)
                    acc[i2][2+jj] = __builtin_amdgcn_mfma_f32_16x16x32_bf16(
                        ar[i2][kk], br[2+jj][kk], acc[i2][2+jj], 0, 0, 0);
        __builtin_amdgcn_s_setprio(0);
        __builtin_amdgcn_s_barrier();

        // ---- phase 3: (A1,B0) ----
#pragma unroll
        for (int i2 = 0; i2 < 4; i2++)
#pragma unroll
            for (int kk = 0; kk < 2; kk++) ar[i2][kk] = rdA(db, 1, i2, kk);
        if (s2) stage(Ab, ASLOT(db,0), 0, kt+2);
        __builtin_amdgcn_s_barrier();
        asm volatile("s_waitcnt lgkmcnt(0)" ::: "memory");
        __builtin_amdgcn_sched_barrier(0);
        __builtin_amdgcn_s_setprio(1);
#pragma unroll
        for (int i2 = 0; i2 < 4; i2++)
#pragma unroll
            for (int jj = 0; jj < 2; jj++)
#pragma unroll
                for (int kk = 0; kk < 2; kk++)
                    acc[4+i2][jj] = __builtin_amdgcn_mfma_f32_16x16x32_bf16(
                        ar[i2][kk], br[jj][kk], acc[4+i2][jj], 0, 0, 0);
        __builtin_amdgcn_s_setprio(0);
        __builtin_amdgcn_s_barrier();

        // ---- phase 4: (A1,B1) ----
        if (s2) stage(Bb, BSLOT(db,0), 0, kt+2);
        if (s2)      { asm volatile("s_waitcnt vmcnt(8)" ::: "memory"); }
        else if (s1) { asm volatile("s_waitcnt vmcnt(4)" ::: "memory"); }
        else         { asm volatile("s_waitcnt vmcnt(0)" ::: "memory"); }
        __builtin_amdgcn_s_barrier();
        __builtin_amdgcn_sched_barrier(0);
        __builtin_amdgcn_s_setprio(1);
#pragma unroll
        for (int i2 = 0; i2 < 4; i2++)
#pragma unroll
            for (int jj = 0; jj < 2; jj++)
#pragma unroll
                for (int kk = 0; kk < 2; kk++)
                    acc[4+i2][2+jj] = __builtin_amdgcn_mfma_f32_16x16x32_bf16(
                        ar[i2][kk], br[2+jj][kk], acc[4+i2][2+jj], 0, 0, 0);
        __builtin_amdgcn_s_setprio(0);
        __builtin_amdgcn_s_barrier();
    }

    // epilogue: C row = m0 + (i>>2)*128 + (i&3)*32 + wm*16 + (l>>4)*4 + v
    //           C col = n0 + j*64 + wn*16 + (l&15)
#pragma unroll
    for (int i = 0; i < 8; i++) {
        size_t row_base = m0 + (size_t)(i>>2)*128 + (i&3)*32 + wm*16 + (l>>4)*4;
#pragma unroll
        for (int j = 0; j < 4; j++) {
            size_t col = n0 + (size_t)j*64 + wn*16 + l15;
#pragma unroll
            for (int v = 0; v < 4; v++) {
                size_t row = row_base + v;
                float val = acc[i][j][v];
                if (MODE == 0) {
                    ((short*)Cout)[row * ldc + col] = (short)f2bf(siluf_(val));
                } else {
                    float* p = (float*)Cout + row * ldc + col;
                    *p = val + *p;
                }
            }
        }
    }
#undef ASLOT
#undef BSLOT
}

extern "C" void kernel_launch(void* const* d_in, const int* in_sizes, int n_in,
                              void* d_out, int out_size, void* d_ws, size_t ws_size,
                              hipStream_t stream)
{
    const float* x    = (const float*)d_in[0];
    const float* n1w  = (const float*)d_in[1];
    const float* n2w  = (const float*)d_in[2];
    const float* araw = (const float*)d_in[3];
    const float* bw   = (const float*)d_in[4];
    const float* cw   = (const float*)d_in[5];
    const float* Wq   = (const float*)d_in[6];
    const float* Wk   = (const float*)d_in[7];
    const float* Wv   = (const float*)d_in[8];
    const float* Wo   = (const float*)d_in[9];
    const float* Wg   = (const float*)d_in[10];
    const float* gb   = (const float*)d_in[11];
    const float* ffw1 = (const float*)d_in[12];
    const float* ffw2 = (const float*)d_in[13];
    float* out = (float*)d_out;

    float* ws    = (float*)d_ws;
    float* rms1  = ws;                                   // N_
    float* gate  = rms1  + N_;                           // N_
    float* cpart = gate  + N_;                           // B_*NCHUNK_*D_
    float* cin   = cpart + (size_t)B_*NCHUNK_*D_;        // B_*NCHUNK_*D_
    float* qb    = cin   + (size_t)B_*NCHUNK_*D_;        // N_*A_
    float* kb    = qb    + (size_t)N_*A_;
    float* vb    = kb    + (size_t)N_*A_;
    float* x_ssm = vb    + (size_t)N_*A_;                // N_*D_ f32
    short* xsb   = (short*)(x_ssm + (size_t)N_*D_);      // N_*D_ bf16
    short* attnb = xsb   + (size_t)N_*D_;                // N_*A_ bf16
    short* a1    = attnb + (size_t)N_*A_;                // N_*D_ bf16
    short* act   = a1    + (size_t)N_*D_;                // N_*FF_ bf16
    short* w1t   = act   + (size_t)N_*FF_;               // FF_*D_ bf16
    short* w2t   = w1t   + (size_t)FF_*D_;               // D_*FF_ bf16
    short* wqkvT = w2t   + (size_t)D_*FF_;               // 192*D_ bf16
    short* wot   = wqkvT + (size_t)192*D_;               // D_*A_ bf16

    // weight convert+transpose
    cvt_transpose<<<dim3(FF_/64, D_/64), 256, 0, stream>>>(ffw1, D_, FF_, w1t);
    cvt_transpose<<<dim3(D_/64, FF_/64), 256, 0, stream>>>(ffw2, FF_, D_, w2t);
    qkv_t3<<<dim3(1, D_/64, 3), 256, 0, stream>>>(Wq, Wk, Wv, wqkvT);
    cvt_transpose<<<dim3(D_/64, 1), 256, 0, stream>>>(Wo, A_, D_, wot);

    // 1. rms of x
    rms_kernel<<<N_/4, 256, 0, stream>>>(x, rms1);
    // 2-4. chunked SSM scan -> x_ssm (f32 + bf16)
    scan1_kernel<<<dim3(D_/64, NCHUNK_, B_), 64, 0, stream>>>(x, rms1, n1w, bw, araw, cpart);
    scan2_kernel<<<(B_*D_)/256, 256, 0, stream>>>(araw, cpart, cin);
    scan3_kernel<<<dim3(D_/64, NCHUNK_, B_), 64, 0, stream>>>(x, rms1, n1w, bw, cw, araw, cin, x_ssm, xsb);
    // 5. q,k,v projections [MFMA]
    qkv_mfma<<<N_/64, 256, 0, stream>>>(xsb, wqkvT, qb, kb, vb);
    // 6. gate
    gate_kernel<<<N_/4, 256, 0, stream>>>(x_ssm, Wg, gb, gate);
    // 7. sliding-window attention (bf16 out)
    attn_kernel<<<dim3(L_/64, B_), 256, 0, stream>>>(qb, kb, vb, attnb);
    // 8. x_att = x_ssm + gate * (attn @ Wo) [MFMA] -> d_out
    gemm_wo<<<dim3(N_/128, D_/128), 256, 0, stream>>>(attnb, wot, gate, x_ssm, out);
    // 9. a1 = bf16(rmsnorm(x_att) * n2w)
    ff1prep<<<N_/4, 256, 0, stream>>>(out, n2w, a1);
    // 10. act = bf16(silu(a1 @ w1)) [MFMA 8-phase]
    gemm8p<D_, 0><<<dim3(N_/256, FF_/256), 512, 0, stream>>>(a1, w1t, (void*)act, FF_);
    // 11. y = x_att + act @ w2 [MFMA 8-phase, in-place]
    gemm8p<FF_, 1><<<dim3(N_/256, D_/256), 512, 0, stream>>>(act, w2t, (void*)out, D_);
}

// Round 5
// 456.594 us; speedup vs baseline: 1.0833x; 1.0833x over previous
//
#include <hip/hip_runtime.h>
#include <math.h>

#define B_ 4
#define L_ 4096
#define D_ 1024
#define A_ 64
#define FF_ 2048
#define N_ (B_*L_)
#define EPS_ 1e-6f
#define CHUNK_ 128
#define NCHUNK_ (L_/CHUNK_)

typedef __attribute__((ext_vector_type(8))) short bf16x8;
typedef __attribute__((ext_vector_type(4))) short s16x4;
typedef __attribute__((ext_vector_type(4))) float f32x4;

static __device__ __forceinline__ float sigmoidf_(float x) { return 1.f/(1.f+expf(-x)); }
static __device__ __forceinline__ float siluf_(float x)    { return x/(1.f+expf(-x)); }

static __device__ __forceinline__ unsigned short f2bf(float f) {
    unsigned u = __float_as_uint(f);
    u += 0x7fffu + ((u >> 16) & 1u);        // RNE
    return (unsigned short)(u >> 16);
}

// async global->LDS, 16B per lane; lds ptr wave-uniform (HW adds lane*16)
static __device__ __forceinline__ void gload16(const short* g, short* l) {
    __builtin_amdgcn_global_load_lds(
        (const __attribute__((address_space(1))) void*)g,
        (__attribute__((address_space(3))) void*)l, 16, 0, 0);
}

// ---------------- rms (one wave per row) ----------------
__global__ __launch_bounds__(256) void rms_kernel(const float* __restrict__ x,
                                                  float* __restrict__ rms)
{
    int row  = blockIdx.x*4 + (threadIdx.x>>6);
    int lane = threadIdx.x & 63;
    const float4* xr = (const float4*)(x + (size_t)row*D_);
    float s = 0.f;
#pragma unroll
    for (int j = 0; j < 4; j++) {
        float4 v = xr[lane + 64*j];
        s += v.x*v.x + v.y*v.y + v.z*v.z + v.w*v.w;
    }
#pragma unroll
    for (int off = 32; off > 0; off >>= 1) s += __shfl_xor(s, off);
    if (lane == 0) rms[row] = rsqrtf(s*(1.f/(float)D_) + EPS_);
}

// ---------------- SSM scan phase 1 ----------------
__global__ __launch_bounds__(64) void scan1_kernel(
    const float* __restrict__ x, const float* __restrict__ rms1,
    const float* __restrict__ n1w, const float* __restrict__ bw,
    const float* __restrict__ araw, float* __restrict__ cpart)
{
    int d = blockIdx.x*64 + threadIdx.x;
    int c = blockIdx.y;
    int b = blockIdx.z;
    float a = sigmoidf_(araw[d]);
    float w = n1w[d]*bw[d];
    float h = 0.f;
    size_t base = ((size_t)b*L_ + (size_t)c*CHUNK_)*D_ + d;
    const float* rp = rms1 + b*L_ + c*CHUNK_;
#pragma unroll 8
    for (int t = 0; t < CHUNK_; t++) {
        float u = x[base + (size_t)t*D_] * rp[t] * w;
        h = a*h + u;
    }
    cpart[((size_t)b*NCHUNK_ + c)*D_ + d] = h;
}

// ---------------- SSM scan phase 2 ----------------
__global__ __launch_bounds__(256) void scan2_kernel(
    const float* __restrict__ araw, const float* __restrict__ cpart,
    float* __restrict__ cin)
{
    int idx = blockIdx.x*256 + threadIdx.x;
    int b = idx >> 10;
    int d = idx & (D_-1);
    float a = sigmoidf_(araw[d]);
    float aT = a;
#pragma unroll
    for (int i = 0; i < 7; i++) aT *= aT;     // a^128
    float cy = 0.f;
    for (int c = 0; c < NCHUNK_; c++) {
        size_t o = ((size_t)b*NCHUNK_ + c)*D_ + d;
        cin[o] = cy;
        cy = aT*cy + cpart[o];
    }
}

// ---------------- SSM scan phase 3: writes x_ssm f32 + bf16 ----------------
__global__ __launch_bounds__(64) void scan3_kernel(
    const float* __restrict__ x, const float* __restrict__ rms1,
    const float* __restrict__ n1w, const float* __restrict__ bw,
    const float* __restrict__ cw, const float* __restrict__ araw,
    const float* __restrict__ cin, float* __restrict__ x_ssm,
    short* __restrict__ xsb)
{
    int d = blockIdx.x*64 + threadIdx.x;
    int c = blockIdx.y;
    int b = blockIdx.z;
    float a = sigmoidf_(araw[d]);
    float w = n1w[d]*bw[d];
    float cwd = cw[d];
    float h = cin[((size_t)b*NCHUNK_ + c)*D_ + d];
    size_t base = ((size_t)b*L_ + (size_t)c*CHUNK_)*D_ + d;
    const float* rp = rms1 + b*L_ + c*CHUNK_;
#pragma unroll 8
    for (int t = 0; t < CHUNK_; t++) {
        size_t p = base + (size_t)t*D_;
        float xv = x[p];
        h = a*h + xv * rp[t] * w;
        float o = xv + h*cwd;
        x_ssm[p] = o;
        xsb[p] = (short)f2bf(o);
    }
}

// ---------------- transpose + f32->bf16 cast: in [R][C] f32 -> out [C][R] bf16 ----------------
__global__ __launch_bounds__(256) void cvt_transpose(
    const float* __restrict__ in, int R, int C, short* __restrict__ out)
{
    __shared__ short sh[64][68];
    int t  = threadIdx.x;
    int c0 = blockIdx.x * 64, r0 = blockIdx.y * 64;
    int rr = t >> 4, cc = (t & 15) * 4;
#pragma unroll
    for (int p = 0; p < 4; p++) {
        int r = p*16 + rr;
        float4 v = *(const float4*)(in + (size_t)(r0 + r)*C + c0 + cc);
        s16x4 sv = { (short)f2bf(v.x), (short)f2bf(v.y), (short)f2bf(v.z), (short)f2bf(v.w) };
        *(s16x4*)&sh[r][cc] = sv;
    }
    __syncthreads();
#pragma unroll
    for (int p = 0; p < 4; p++) {
        int c = p*16 + rr;
        s16x4 ov = { sh[cc+0][c], sh[cc+1][c], sh[cc+2][c], sh[cc+3][c] };
        *(s16x4*)(out + (size_t)(c0 + c)*R + r0 + cc) = ov;
    }
}

// ---------------- merged QKV weight transpose: 3x [D_][A_] f32 -> [A_][D_] bf16 ----------------
__global__ __launch_bounds__(256) void qkv_t3(
    const float* __restrict__ Wq, const float* __restrict__ Wk,
    const float* __restrict__ Wv, short* __restrict__ outall)
{
    __shared__ short sh[64][68];
    const float* in = (blockIdx.z == 0) ? Wq : (blockIdx.z == 1) ? Wk : Wv;
    short* out = outall + (size_t)blockIdx.z * A_ * D_;
    int t  = threadIdx.x;
    int r0 = blockIdx.y * 64;
    int rr = t >> 4, cc = (t & 15) * 4;
#pragma unroll
    for (int p = 0; p < 4; p++) {
        int r = p*16 + rr;
        float4 v = *(const float4*)(in + (size_t)(r0 + r)*A_ + cc);
        s16x4 sv = { (short)f2bf(v.x), (short)f2bf(v.y), (short)f2bf(v.z), (short)f2bf(v.w) };
        *(s16x4*)&sh[r][cc] = sv;
    }
    __syncthreads();
#pragma unroll
    for (int p = 0; p < 4; p++) {
        int c = p*16 + rr;
        s16x4 ov = { sh[cc+0][c], sh[cc+1][c], sh[cc+2][c], sh[cc+3][c] };
        *(s16x4*)(out + (size_t)c*D_ + r0 + cc) = ov;
    }
}

// ---------------- Wg -> weight row 192; rows 193..207 zero ----------------
__global__ __launch_bounds__(256) void wg_prep(const float* __restrict__ Wg,
                                               short* __restrict__ wqkvT)
{
    int d = blockIdx.x*256 + threadIdx.x;
    wqkvT[(size_t)192*D_ + d] = (short)f2bf(Wg[d]);
#pragma unroll
    for (int r = 193; r < 208; r++) wqkvT[(size_t)r*D_ + d] = 0;
}

// ---------------- fused rmsnorm2 + bf16 cast ----------------
__global__ __launch_bounds__(256) void ff1prep(
    const float* __restrict__ xatt, const float* __restrict__ n2w,
    short* __restrict__ a1)
{
    int row  = blockIdx.x*4 + (threadIdx.x>>6);
    int lane = threadIdx.x & 63;
    const float4* xr = (const float4*)(xatt + (size_t)row*D_);
    const float4* wr = (const float4*)n2w;
    float4 v[4];
    float s = 0.f;
#pragma unroll
    for (int j = 0; j < 4; j++) {
        v[j] = xr[lane + 64*j];
        s += v[j].x*v[j].x + v[j].y*v[j].y + v[j].z*v[j].z + v[j].w*v[j].w;
    }
#pragma unroll
    for (int off = 32; off > 0; off >>= 1) s += __shfl_xor(s, off);
    float r = rsqrtf(s*(1.f/(float)D_) + EPS_);
#pragma unroll
    for (int j = 0; j < 4; j++) {
        float4 w = wr[lane + 64*j];
        s16x4 o = { (short)f2bf(v[j].x*r*w.x), (short)f2bf(v[j].y*r*w.y),
                    (short)f2bf(v[j].z*r*w.z), (short)f2bf(v[j].w*r*w.w) };
        *(s16x4*)(a1 + (size_t)row*D_ + (lane + 64*j)*4) = o;
    }
}

// ---------------- QKV+gate: [N_][1024]bf16 @ [208][1024]bf16^T -> q,k,v bf16; vbt; gate ----------------
__global__ __launch_bounds__(256) void qkv_mfma(
    const short* __restrict__ A, const short* __restrict__ BT,
    short* __restrict__ qo, short* __restrict__ ko, short* __restrict__ vo,
    short* __restrict__ vbt, float* __restrict__ gate,
    const float* __restrict__ gb)
{
    __shared__ short As2[2][64*32];
    __shared__ short Bs2[2][208*32];
    const int t = threadIdx.x, l = t & 63, w = t >> 6;
    const int l15 = l & 15;
    const size_t m0 = (size_t)blockIdx.x*64;
    const short* Ab = A + m0*D_;

    const int ar = w*16 + l15;
    const int offA = ar*32 + (((l>>4) ^ ((ar>>1)&3)) & 3)*8;
    int offB[13];
#pragma unroll
    for (int j = 0; j < 13; j++) {
        int br = j*16 + l15;
        offB[j] = br*32 + (((l>>4) ^ ((br>>1)&3)) & 3)*8;
    }

#define QSTG(bi, k0) { \
        { int r = t>>2; int lc = (t&3) ^ ((r>>1)&3); \
          gload16(Ab + (size_t)r*D_ + (k0) + lc*8, &As2[bi][(w*64)*8]); } \
        _Pragma("unroll") \
        for (int i_ = 0; i_ < 3; i_++) { \
            int s_ = i_*256 + t; int r = s_>>2; int lc = (s_&3) ^ ((r>>1)&3); \
            gload16(BT + (size_t)r*D_ + (k0) + lc*8, &Bs2[bi][(i_*256 + w*64)*8]); } \
        if (w == 0) { int r = 192 + (l>>2); int lc = (l&3) ^ ((r>>1)&3); \
            gload16(BT + (size_t)r*D_ + (k0) + lc*8, &Bs2[bi][768*8]); } }

    f32x4 acc[13];
    f32x4 zero = {0.f,0.f,0.f,0.f};
#pragma unroll
    for (int j = 0; j < 13; j++) acc[j] = zero;

    QSTG(0, 0);
    __syncthreads();
    int cur = 0;
    for (int kt = 0; kt < 32; kt++) {
        if (kt + 1 < 32) QSTG(cur^1, (kt+1)*32);
        bf16x8 af = *(const bf16x8*)&As2[cur][offA];
#pragma unroll
        for (int j = 0; j < 13; j++) {
            bf16x8 bfv = *(const bf16x8*)&Bs2[cur][offB[j]];
            acc[j] = __builtin_amdgcn_mfma_f32_16x16x32_bf16(af, bfv, acc[j], 0, 0, 0);
        }
        __syncthreads();
        cur ^= 1;
    }
#pragma unroll
    for (int j = 0; j < 12; j++) {
        int col = j*16 + l15;
        int mat = col >> 6, c = col & 63;
        short* dst = (mat == 0) ? qo : (mat == 1) ? ko : vo;
#pragma unroll
        for (int v = 0; v < 4; v++) {
            size_t row = m0 + w*16 + (l>>4)*4 + v;
            dst[row*A_ + c] = (short)f2bf(acc[j][v]);
        }
    }
    // transposed V copy: vbt[b][dim][L]
#pragma unroll
    for (int j = 8; j < 12; j++) {
        int c = j*16 + l15 - 128;
#pragma unroll
        for (int v = 0; v < 4; v++) {
            size_t row = m0 + w*16 + (l>>4)*4 + v;
            size_t bb = row >> 12;
            size_t lr = row & (L_-1);
            vbt[(bb*A_ + c)*L_ + lr] = (short)f2bf(acc[j][v]);
        }
    }
    // gate from tile 12 col 192
    if (l15 == 0) {
        float g0 = gb[0];
#pragma unroll
        for (int v = 0; v < 4; v++) {
            size_t row = m0 + w*16 + (l>>4)*4 + v;
            gate[row] = sigmoidf_(acc[12][v] + g0);
        }
    }
#undef QSTG
}

// ---------------- MFMA sliding-window attention: 64 q/block, 4 waves ----------------
__global__ __launch_bounds__(256) void attn_mfma(
    const short* __restrict__ qb, const short* __restrict__ kb,
    const short* __restrict__ vbt, short* __restrict__ om)
{
    __shared__ short Ks[128*64];   // [key][d], rows 128B, XOR-swizzled
    __shared__ short Vs[64*128];   // [d][key], rows 256B, XOR-swizzled
    __shared__ short Ps[64*128];   // [q][key], rows 256B, XOR-swizzled
    const int b  = blockIdx.y;
    const int l0 = blockIdx.x*64;
    const int t  = threadIdx.x, l = t & 63, w = t >> 6;
    const int l15 = l & 15;

    // stage K rows l0-64 .. l0+63 (clamped; garbage masked later)
#pragma unroll
    for (int u = 0; u < 4; u++) {
        int seg = w*4 + u;
        int row = seg*8 + (l>>3);
        int unit = (l&7) ^ (row&7);
        int key = l0 - 64 + row; if (key < 0) key = 0;
        gload16(kb + ((size_t)b*L_ + key)*A_ + unit*8, Ks + seg*512);
    }
    // stage V^T [d][128 keys]
#pragma unroll
    for (int u = 0; u < 4; u++) {
        int seg = w*4 + u;
        int row = seg*4 + (l>>4);
        int unit = l15 ^ (row&7);
        int key = l0 - 64 + unit*8; if (key < 0) key = 0;
        gload16(vbt + ((size_t)b*A_ + row)*L_ + key, Vs + seg*512);
    }
    // Q frags from global (this wave's 16 rows)
    bf16x8 qf[2];
    {
        const short* qrow = qb + ((size_t)b*L_ + l0 + w*16 + l15)*A_ + (l>>4)*8;
        qf[0] = *(const bf16x8*)(qrow);
        qf[1] = *(const bf16x8*)(qrow + 32);
    }
    asm volatile("s_waitcnt vmcnt(0)" ::: "memory");
    __builtin_amdgcn_s_barrier();

    // S = Q K^T  (wave w -> q-tile w; 8 key-tiles)
    f32x4 sacc[8];
    f32x4 zero = {0.f,0.f,0.f,0.f};
#pragma unroll
    for (int j = 0; j < 8; j++) sacc[j] = zero;
#pragma unroll
    for (int j = 0; j < 8; j++) {
#pragma unroll
        for (int ks = 0; ks < 2; ks++) {
            int row = j*16 + l15;
            bf16x8 kf = *(const bf16x8*)(Ks + ((row*128 + ((ks*64 + (l>>4)*16) ^ ((row&7)*16))) >> 1));
            sacc[j] = __builtin_amdgcn_mfma_f32_16x16x32_bf16(qf[ks], kf, sacc[j], 0, 0, 0);
        }
    }

    // band-masked softmax per row (rows live in 16-lane groups)
#pragma unroll
    for (int v = 0; v < 4; v++) {
        int gq = l0 + w*16 + (l>>4)*4 + v;
        float m = -1e30f;
#pragma unroll
        for (int j = 0; j < 8; j++) {
            int gk = l0 - 64 + j*16 + l15;
            bool ok = (gk >= 0) && (gk <= gq) && (gk >= gq - 63);
            float sv = ok ? sacc[j][v]*0.125f : -1e30f;
            sacc[j][v] = sv;
            m = fmaxf(m, sv);
        }
        m = fmaxf(m, __shfl_xor(m, 1));
        m = fmaxf(m, __shfl_xor(m, 2));
        m = fmaxf(m, __shfl_xor(m, 4));
        m = fmaxf(m, __shfl_xor(m, 8));
        float s = 0.f;
#pragma unroll
        for (int j = 0; j < 8; j++) { float e = expf(sacc[j][v] - m); sacc[j][v] = e; s += e; }
        s += __shfl_xor(s, 1); s += __shfl_xor(s, 2);
        s += __shfl_xor(s, 4); s += __shfl_xor(s, 8);
        float inv = 1.f/s;
#pragma unroll
        for (int j = 0; j < 8; j++) sacc[j][v] *= inv;
    }

    // P -> LDS bf16 (XOR-swizzled); read back by SAME wave only
#pragma unroll
    for (int j = 0; j < 8; j++) {
#pragma unroll
        for (int v = 0; v < 4; v++) {
            int qr = w*16 + (l>>4)*4 + v;
            int key = j*16 + l15;
            Ps[qr*128 + (((key>>3) ^ (qr&7))*8 + (key&7))] = (short)f2bf(sacc[j][v]);
        }
    }
    asm volatile("s_waitcnt lgkmcnt(0)" ::: "memory");

    // O = P V
    f32x4 oacc[4];
#pragma unroll
    for (int dt = 0; dt < 4; dt++) oacc[dt] = zero;
#pragma unroll
    for (int ks = 0; ks < 4; ks++) {
        int qr = w*16 + l15;
        bf16x8 pf = *(const bf16x8*)(Ps + qr*128 + (((ks*4 + (l>>4)) ^ (qr&7))*8));
#pragma unroll
        for (int dt = 0; dt < 4; dt++) {
            int vr = dt*16 + l15;
            bf16x8 vf = *(const bf16x8*)(Vs + vr*128 + (((ks*4 + (l>>4)) ^ (vr&7))*8));
            oacc[dt] = __builtin_amdgcn_mfma_f32_16x16x32_bf16(pf, vf, oacc[dt], 0, 0, 0);
        }
    }
#pragma unroll
    for (int dt = 0; dt < 4; dt++) {
#pragma unroll
        for (int v = 0; v < 4; v++) {
            int gq = l0 + w*16 + (l>>4)*4 + v;
            om[((size_t)b*L_ + gq)*A_ + dt*16 + l15] = (short)f2bf(oacc[dt][v]);
        }
    }
}

// ---------------- WO: out = resid + gate*(attn_bf16 @ wot^T), K=64 ----------------
__global__ __launch_bounds__(256) void gemm_wo(
    const short* __restrict__ A, const short* __restrict__ BT,
    const float* __restrict__ gate, const float* __restrict__ resid,
    float* __restrict__ Cout)
{
    __shared__ short As3[128*64];
    __shared__ short Bs3[128*64];
    const int t = threadIdx.x, l = t & 63, w = t >> 6;
    const int wm = w >> 1, wn = w & 1;
    const size_t m0 = (size_t)blockIdx.x*128, n0 = (size_t)blockIdx.y*128;

#pragma unroll
    for (int i = 0; i < 4; i++) {
        int s = i*256 + t;
        int r = s >> 3, lc = (s&7) ^ (r&7);
        gload16(A  + (m0 + r)*64 + lc*8, &As3[(i*256 + w*64)*8]);
        gload16(BT + (n0 + r)*64 + lc*8, &Bs3[(i*256 + w*64)*8]);
    }
    __syncthreads();

    f32x4 acc[4][4];
    f32x4 zero = {0.f,0.f,0.f,0.f};
#pragma unroll
    for (int i = 0; i < 4; i++)
#pragma unroll
        for (int j = 0; j < 4; j++) acc[i][j] = zero;

#pragma unroll
    for (int kk = 0; kk < 2; kk++) {
        bf16x8 af[4], bfv[4];
#pragma unroll
        for (int i = 0; i < 4; i++) {
            int ar = wm*64 + i*16 + (l&15);
            int pch = (kk*4 + (l>>4)) ^ (ar&7);
            af[i] = *(const bf16x8*)&As3[ar*64 + pch*8];
        }
#pragma unroll
        for (int j = 0; j < 4; j++) {
            int br = wn*64 + j*16 + (l&15);
            int pch = (kk*4 + (l>>4)) ^ (br&7);
            bfv[j] = *(const bf16x8*)&Bs3[br*64 + pch*8];
        }
#pragma unroll
        for (int i = 0; i < 4; i++)
#pragma unroll
            for (int j = 0; j < 4; j++)
                acc[i][j] = __builtin_amdgcn_mfma_f32_16x16x32_bf16(af[i], bfv[j], acc[i][j], 0, 0, 0);
    }

#pragma unroll
    for (int i = 0; i < 4; i++) {
#pragma unroll
        for (int v = 0; v < 4; v++) {
            size_t row = m0 + wm*64 + i*16 + (l>>4)*4 + v;
            float g = gate[row];
#pragma unroll
            for (int j = 0; j < 4; j++) {
                size_t col = n0 + wn*64 + j*16 + (l&15);
                Cout[row*D_ + col] = resid[row*D_ + col] + g*acc[i][j][v];
            }
        }
    }
}

// ---------------- 8-phase 256x256 bf16 GEMM, BK=64, hoisted addressing, 1 vmcnt/K-tile ----------------
// MODE 0: Cout bf16 = silu(acc); MODE 1: Cout f32 += acc
template<int K, int MODE>
__global__ __launch_bounds__(512, 2) void gemm8p(
    const short* __restrict__ A, const short* __restrict__ BT,
    void* __restrict__ Cout, int ldc)
{
    __shared__ short LDSb[65536];  // A halves: [0,32768) shorts; B: [32768,65536)

    const int gx = gridDim.x, gy = gridDim.y;
    const int nwg = gx*gy;
    const int o = blockIdx.y*gx + blockIdx.x;
    const int q = nwg >> 3;
    const int swz = (o & 7)*q + (o >> 3);
    const int bx = swz / gy, by = swz % gy;

    const int t = threadIdx.x, l = t & 63, w = t >> 6;
    const int wm = w & 1, wn = w >> 1;
    const size_t m0 = (size_t)bx*256, n0 = (size_t)by*256;

    const int l15 = l & 15;
    const int l16 = (l >> 4) * 16;
    const int xsw = (l15 & 7) * 16;
    // 4 hoisted ds_read base pointers (kk=0/1 for A and B); everything else is an immediate
    const short* pA0 = LDSb + (((wm*16 + l15)*128 + (l16 ^ xsw)) >> 1);
    const short* pA1 = LDSb + (((wm*16 + l15)*128 + ((64 + l16) ^ xsw)) >> 1);
    const short* pB0 = LDSb + 32768 + (((wn*16 + l15)*128 + (l16 ^ xsw)) >> 1);
    const short* pB1 = LDSb + 32768 + (((wn*16 + l15)*128 + ((64 + l16) ^ xsw)) >> 1);

    // staging bases: lane covers row (l>>3) of wave's 8-row chunk; source col pre-swizzled
    const int srow = l >> 3;
    const int scol = ((l & 7) ^ srow) * 8;
    const short* gA = A  + m0*(size_t)K + (size_t)(w*8 + srow)*K + scol;
    const short* gB = BT + n0*(size_t)K + (size_t)(w*8 + srow)*K + scol;
    short* ldsA = (short*)LDSb + w*512;
    short* ldsB = (short*)LDSb + 32768 + w*512;

#define STG_A(DB,H,TO) { \
    gload16(gA + (H)*128*K + (TO)*64,        ldsA + (DB)*16384 + (H)*8192); \
    gload16(gA + (H)*128*K + 64*K + (TO)*64, ldsA + (DB)*16384 + (H)*8192 + 4096); }
#define STG_B(DB,H,TO) { \
    gload16(gB + (H)*128*K + (TO)*64,        ldsB + (DB)*16384 + (H)*8192); \
    gload16(gB + (H)*128*K + 64*K + (TO)*64, ldsB + (DB)*16384 + (H)*8192 + 4096); }
#define RD_A(DB,H,IP,KK) (*(const bf16x8*)(((KK) ? pA1 : pA0) + (DB)*16384 + (H)*8192 + (IP)*2048))
#define RD_B(DB,H,JR,KK) (*(const bf16x8*)(((KK) ? pB1 : pB0) + (DB)*16384 + (H)*8192 + (JR)*4096))
#define MFMA16(IO,JO) \
    _Pragma("unroll") for (int i2 = 0; i2 < 4; i2++) \
    _Pragma("unroll") for (int jj = 0; jj < 2; jj++) \
    _Pragma("unroll") for (int kk = 0; kk < 2; kk++) \
        acc[(IO)+i2][(JO)+jj] = __builtin_amdgcn_mfma_f32_16x16x32_bf16( \
            ar[i2][kk], br[(JO)+jj][kk], acc[(IO)+i2][(JO)+jj], 0, 0, 0);
#define PH_SYNC \
    __builtin_amdgcn_s_barrier(); \
    asm volatile("s_waitcnt lgkmcnt(0)" ::: "memory"); \
    __builtin_amdgcn_sched_barrier(0);

#define TILE(DB,S1,S2) { \
    /* phase 1: (A0,B0) */ \
    _Pragma("unroll") for (int i2 = 0; i2 < 4; i2++) { \
        ar[i2][0] = RD_A(DB,0,i2,0); ar[i2][1] = RD_A(DB,0,i2,1); } \
    _Pragma("unroll") for (int jj = 0; jj < 2; jj++) { \
        br[jj][0] = RD_B(DB,0,jj,0); br[jj][1] = RD_B(DB,0,jj,1); } \
    if (S1) { STG_A(1-(DB),1,1); \
              asm volatile("s_waitcnt vmcnt(6)" ::: "memory"); } \
    else    { asm volatile("s_waitcnt vmcnt(0)" ::: "memory"); } \
    PH_SYNC \
    __builtin_amdgcn_s_setprio(1); MFMA16(0,0) __builtin_amdgcn_s_setprio(0); \
    __builtin_amdgcn_s_barrier(); \
    /* phase 2: (A0,B1) */ \
    _Pragma("unroll") for (int jj = 0; jj < 2; jj++) { \
        br[2+jj][0] = RD_B(DB,1,jj,0); br[2+jj][1] = RD_B(DB,1,jj,1); } \
    if (S1) STG_B(1-(DB),1,1); \
    PH_SYNC \
    __builtin_amdgcn_s_setprio(1); MFMA16(0,2) __builtin_amdgcn_s_setprio(0); \
    __builtin_amdgcn_s_barrier(); \
    /* phase 3: (A1,B0) */ \
    _Pragma("unroll") for (int i2 = 0; i2 < 4; i2++) { \
        ar[i2][0] = RD_A(DB,1,i2,0); ar[i2][1] = RD_A(DB,1,i2,1); } \
    if (S2) STG_A(DB,0,2); \
    PH_SYNC \
    __builtin_amdgcn_s_setprio(1); MFMA16(4,0) __builtin_amdgcn_s_setprio(0); \
    __builtin_amdgcn_s_barrier(); \
    /* phase 4: (A1,B1) */ \
    if (S2) STG_B(DB,0,2); \
    __builtin_amdgcn_s_barrier(); \
    __builtin_amdgcn_sched_barrier(0); \
    __builtin_amdgcn_s_setprio(1); MFMA16(4,2) __builtin_amdgcn_s_setprio(0); \
    __builtin_amdgcn_s_barrier(); \
    gA += 64; gB += 64; }

    f32x4 acc[8][4];
    f32x4 zero = {0.f,0.f,0.f,0.f};
#pragma unroll
    for (int i = 0; i < 8; i++)
#pragma unroll
        for (int j = 0; j < 4; j++) acc[i][j] = zero;
    bf16x8 ar[4][2], br[4][2];

    // prologue: tile0 all halves + tile1 (A0,B0); wait tile0 (A0,B0) landed
    STG_A(0,0,0); STG_B(0,0,0);
    STG_A(0,1,0); STG_B(0,1,0);
    STG_A(1,0,1); STG_B(1,0,1);
    asm volatile("s_waitcnt vmcnt(8)" ::: "memory");
    __builtin_amdgcn_s_barrier();

    const int nk = K >> 6;
#pragma unroll 1
    for (int kt2 = 0; kt2 < nk/2 - 1; kt2++) {
        TILE(0,1,1)
        TILE(1,1,1)
    }
    TILE(0,1,0)
    TILE(1,0,0)

    // epilogue
#pragma unroll
    for (int i = 0; i < 8; i++) {
        size_t row_base = m0 + (size_t)(i>>2)*128 + (i&3)*32 + wm*16 + (l>>4)*4;
#pragma unroll
        for (int j = 0; j < 4; j++) {
            size_t col = n0 + (size_t)j*64 + wn*16 + l15;
#pragma unroll
            for (int v = 0; v < 4; v++) {
                size_t row = row_base + v;
                float val = acc[i][j][v];
                if (MODE == 0) {
                    ((short*)Cout)[row * ldc + col] = (short)f2bf(siluf_(val));
                } else {
                    float* p = (float*)Cout + row * ldc + col;
                    *p = val + *p;
                }
            }
        }
    }
#undef STG_A
#undef STG_B
#undef RD_A
#undef RD_B
#undef MFMA16
#undef PH_SYNC
#undef TILE
}

extern "C" void kernel_launch(void* const* d_in, const int* in_sizes, int n_in,
                              void* d_out, int out_size, void* d_ws, size_t ws_size,
                              hipStream_t stream)
{
    const float* x    = (const float*)d_in[0];
    const float* n1w  = (const float*)d_in[1];
    const float* n2w  = (const float*)d_in[2];
    const float* araw = (const float*)d_in[3];
    const float* bw   = (const float*)d_in[4];
    const float* cw   = (const float*)d_in[5];
    const float* Wq   = (const float*)d_in[6];
    const float* Wk   = (const float*)d_in[7];
    const float* Wv   = (const float*)d_in[8];
    const float* Wo   = (const float*)d_in[9];
    const float* Wg   = (const float*)d_in[10];
    const float* gb   = (const float*)d_in[11];
    const float* ffw1 = (const float*)d_in[12];
    const float* ffw2 = (const float*)d_in[13];
    float* out = (float*)d_out;

    float* ws    = (float*)d_ws;
    float* rms1  = ws;                                   // N_
    float* gate  = rms1  + N_;                           // N_
    float* cpart = gate  + N_;                           // B_*NCHUNK_*D_
    float* cin   = cpart + (size_t)B_*NCHUNK_*D_;        // B_*NCHUNK_*D_
    float* x_ssm = cin   + (size_t)B_*NCHUNK_*D_;        // N_*D_ f32
    short* xsb   = (short*)(x_ssm + (size_t)N_*D_);      // N_*D_ bf16
    short* qb    = xsb   + (size_t)N_*D_;                // N_*A_ bf16
    short* kb    = qb    + (size_t)N_*A_;
    short* vb    = kb    + (size_t)N_*A_;
    short* vbt   = vb    + (size_t)N_*A_;                // B_*A_*L_ bf16
    short* attnb = vbt   + (size_t)N_*A_;                // N_*A_ bf16
    short* a1    = attnb + (size_t)N_*A_;                // N_*D_ bf16
    short* act   = a1    + (size_t)N_*D_;                // N_*FF_ bf16
    short* w1t   = act   + (size_t)N_*FF_;               // FF_*D_ bf16
    short* w2t   = w1t   + (size_t)FF_*D_;               // D_*FF_ bf16
    short* wqkvT = w2t   + (size_t)D_*FF_;               // 208*D_ bf16
    short* wot   = wqkvT + (size_t)208*D_;               // D_*A_ bf16

    // weight prep
    cvt_transpose<<<dim3(FF_/64, D_/64), 256, 0, stream>>>(ffw1, D_, FF_, w1t);
    cvt_transpose<<<dim3(D_/64, FF_/64), 256, 0, stream>>>(ffw2, FF_, D_, w2t);
    qkv_t3<<<dim3(1, D_/64, 3), 256, 0, stream>>>(Wq, Wk, Wv, wqkvT);
    wg_prep<<<D_/256, 256, 0, stream>>>(Wg, wqkvT);
    cvt_transpose<<<dim3(D_/64, 1), 256, 0, stream>>>(Wo, A_, D_, wot);

    // 1. rms of x
    rms_kernel<<<N_/4, 256, 0, stream>>>(x, rms1);
    // 2-4. chunked SSM scan -> x_ssm (f32 + bf16)
    scan1_kernel<<<dim3(D_/64, NCHUNK_, B_), 64, 0, stream>>>(x, rms1, n1w, bw, araw, cpart);
    scan2_kernel<<<(B_*D_)/256, 256, 0, stream>>>(araw, cpart, cin);
    scan3_kernel<<<dim3(D_/64, NCHUNK_, B_), 64, 0, stream>>>(x, rms1, n1w, bw, cw, araw, cin, x_ssm, xsb);
    // 5. q,k,v (bf16) + vbt + gate [MFMA]
    qkv_mfma<<<N_/64, 256, 0, stream>>>(xsb, wqkvT, qb, kb, vb, vbt, gate, gb);
    // 6. sliding-window attention [MFMA]
    attn_mfma<<<dim3(L_/64, B_), 256, 0, stream>>>(qb, kb, vbt, attnb);
    // 7. x_att = x_ssm + gate * (attn @ Wo) [MFMA] -> d_out
    gemm_wo<<<dim3(N_/128, D_/128), 256, 0, stream>>>(attnb, wot, gate, x_ssm, out);
    // 8. a1 = bf16(rmsnorm(x_att) * n2w)
    ff1prep<<<N_/4, 256, 0, stream>>>(out, n2w, a1);
    // 9. act = bf16(silu(a1 @ w1)) [MFMA 8-phase]
    gemm8p<D_, 0><<<dim3(N_/256, FF_/256), 512, 0, stream>>>(a1, w1t, (void*)act, FF_);
    // 10. y = x_att + act @ w2 [MFMA 8-phase, in-place]
    gemm8p<FF_, 1><<<dim3(N_/256, D_/256), 512, 0, stream>>>(act, w2t, (void*)out, D_);
}